// Round 2
// baseline (10316.929 us; speedup 1.0000x reference)
//
#include <hip/hip_runtime.h>
#include <stdint.h>

// Problem constants
#define BB 64
#define SS 512
#define EE 128
#define HH 256
#define KK 20
#define NEGV -9999.0f
#define SOS_IDX 19

typedef unsigned int u32;

__device__ __forceinline__ float bf_lo(u32 u){ return __uint_as_float(u << 16); }
__device__ __forceinline__ float bf_hi(u32 u){ return __uint_as_float(u & 0xffff0000u); }
__device__ __forceinline__ unsigned short f2b(float f){
  u32 u = __float_as_uint(f);
  u = (u + 0x7fffu + ((u >> 16) & 1u)) >> 16;  // RNE
  return (unsigned short)u;
}
__device__ __forceinline__ float b2f(unsigned short s){ return __uint_as_float(((u32)s) << 16); }
__device__ __forceinline__ float sigm(float x){ return 1.0f / (1.0f + __expf(-x)); }

// ---- K0a: repack W_hh (f32 [1024][256]) -> f32 wt2[d][kq(64)][row(1024)][4]
// so lstm thread `row` loads float4 per kq, coalesced across rows.
__global__ void prep_whh(const float* __restrict__ whh_f, const float* __restrict__ whh_b,
                         float* __restrict__ wt2){
  int id = blockIdx.x * 256 + threadIdx.x;      // 2*1024*256 = 524288
  if (id >= 524288) return;
  int d = id >> 18;
  int rem = id & 262143;
  int row = rem >> 8;
  int k = rem & 255;
  const float* w = d ? whh_b : whh_f;
  wt2[(((size_t)d * 64 + (k >> 2)) * 1024 + row) * 4 + (k & 3)] = w[row * 256 + k];
}

// ---- K0b: transpose W_ih -> wt[k(128)][2048] f32 (cols 0..1023 fwd, 1024..2047 bwd)
__global__ void prep_wih(const float* __restrict__ wih_f, const float* __restrict__ wih_b,
                         float* __restrict__ wt){
  int id = blockIdx.x * 256 + threadIdx.x;      // 2*1024*128 = 262144
  if (id >= 262144) return;
  int d = id >> 17;
  int rem = id & 131071;
  int col = rem >> 7;
  int k = rem & 127;
  const float* w = d ? wih_b : wih_f;
  wt[(size_t)k * 2048 + d * 1024 + col] = w[col * 128 + k];
}

// ---- K1: xg = embed[word] @ W_ih.T + b, both dirs, stored bf16.
// WG = 256 thr covers 16 rows x 1024 cols (cb selects fwd/bwd half).
__global__ __launch_bounds__(256) void xg_gemm(const int* __restrict__ word_seq,
    const float* __restrict__ embed, const float* __restrict__ wt,
    const float* __restrict__ b_f, const float* __restrict__ b_b,
    unsigned short* __restrict__ xg){
  __shared__ __align__(16) float xs[16][128];
  int rb = blockIdx.x >> 1, cb = blockIdx.x & 1;
  int tid = threadIdx.x;
  {
    int r = tid >> 4, kq = (tid & 15) * 8;
    int bs = rb * 16 + r;
    int w = word_seq[bs];
    const float* er = embed + (size_t)w * 128 + kq;
    float4 a = *(const float4*)er;
    float4 b = *(const float4*)(er + 4);
    *(float4*)&xs[r][kq] = a;
    *(float4*)&xs[r][kq + 4] = b;
  }
  __syncthreads();
  int co = tid * 4;
  const float* bias = cb ? b_b : b_f;
  float4 bv = *(const float4*)(bias + co);
  float4 acc[16];
  #pragma unroll
  for (int r = 0; r < 16; r++) acc[r] = bv;
  const float* wptr = wt + cb * 1024 + co;
  for (int k = 0; k < 128; k++){
    float4 w4 = *(const float4*)(wptr + (size_t)k * 2048);
    #pragma unroll
    for (int r = 0; r < 16; r++){
      float xv = xs[r][k];
      acc[r].x += xv * w4.x; acc[r].y += xv * w4.y;
      acc[r].z += xv * w4.z; acc[r].w += xv * w4.w;
    }
  }
  unsigned short* base = xg + (size_t)cb * ((size_t)BB * SS * 1024);
  #pragma unroll
  for (int r = 0; r < 16; r++){
    int bs = rb * 16 + r;
    unsigned short* o = base + (size_t)bs * 1024 + co;
    ushort4 pk;
    pk.x = f2b(acc[r].x); pk.y = f2b(acc[r].y);
    pk.z = f2b(acc[r].z); pk.w = f2b(acc[r].w);
    *(ushort4*)o = pk;
  }
}

// ---- K2: sequential LSTM, one WG (1024 thr) per (batch, dir).
// Thread tid owns gate-row tid; its 256 f32 W_hh weights live in 256 VGPRs
// for the whole kernel (zero weight memory traffic in steady state).
// h state f32 in LDS (broadcast reads), c in regs of threads 0..255.
__global__ __launch_bounds__(1024, 4) void lstm_seq(const int* __restrict__ lengths,
    const float* __restrict__ wt2, const unsigned short* __restrict__ xg,
    float* __restrict__ rnn){
  int bx = blockIdx.x;
  int b = bx & 63, d = bx >> 6;
  int tid = threadIdx.x;
  int l = lengths[b];
  // load weights into registers (coalesced: per kq, 1024 threads read contiguous float4s)
  const float4* wp = (const float4*)(wt2 + (size_t)d * 262144);
  float4 w[64];
  #pragma unroll
  for (int kq = 0; kq < 64; kq++) w[kq] = wp[kq * 1024 + tid];
  __shared__ __align__(16) float hl[256];
  __shared__ float gl[1024];
  if (tid < 256) hl[tid] = 0.f;
  float c = 0.f;
  const unsigned short* xgd = xg + (size_t)d * ((size_t)BB * SS * 1024) + (size_t)b * SS * 1024;
  float* rb = rnn + (size_t)b * SS * 512 + d * 256;
  // zero-fill padded outputs (reference: masked steps output 0)
  for (int i = tid; i < (SS - l) * 256; i += 1024){
    int s = l + (i >> 8), j = i & 255;
    rb[(size_t)s * 512 + j] = 0.f;
  }
  int gate = tid >> 8;          // 0:i 1:f 2:g 3:o — uniform per wave (256-aligned)
  __syncthreads();
  for (int t = 0; t < l; t++){
    int s = d ? (l - 1 - t) : t;
    float xv = b2f(xgd[(size_t)s * 1024 + tid]);   // prefetched: consumed after dot loop
    float a0 = 0.f, a1 = 0.f, a2 = 0.f, a3 = 0.f;
    #pragma unroll
    for (int kq = 0; kq < 16; kq++){
      float4 ha = *(const float4*)&hl[kq * 16];
      float4 hb = *(const float4*)&hl[kq * 16 + 4];
      float4 hc = *(const float4*)&hl[kq * 16 + 8];
      float4 hd = *(const float4*)&hl[kq * 16 + 12];
      float4 wa = w[kq * 4], wb = w[kq * 4 + 1], wc = w[kq * 4 + 2], wd = w[kq * 4 + 3];
      a0 += wa.x * ha.x + wa.y * ha.y + wa.z * ha.z + wa.w * ha.w;
      a1 += wb.x * hb.x + wb.y * hb.y + wb.z * hb.z + wb.w * hb.w;
      a2 += wc.x * hc.x + wc.y * hc.y + wc.z * hc.z + wc.w * hc.w;
      a3 += wd.x * hd.x + wd.y * hd.y + wd.z * hd.z + wd.w * hd.w;
    }
    float a = (a0 + a1) + (a2 + a3) + xv;
    float gv = (gate == 2) ? tanhf(a) : sigm(a);
    gl[tid] = gv;
    __syncthreads();
    if (tid < 256){
      float iv = gl[tid], fv = gl[tid + 256], ggv = gl[tid + 512], ov = gl[tid + 768];
      c = fv * c + iv * ggv;
      float h = ov * tanhf(c);
      hl[tid] = h;
      rb[(size_t)s * 512 + tid] = h;
    }
    __syncthreads();
  }
}

// ---- K3: feats = rnn_out @ lin_W.T + lin_b  (one thread per (row,col)), rnn f32
__global__ void feat_gemv(const float* __restrict__ rnn,
    const float* __restrict__ linW, const float* __restrict__ linb,
    float* __restrict__ feats){
  int id = blockIdx.x * 256 + threadIdx.x;
  if (id >= BB * SS * KK) return;
  int row = id / 20;
  int col = id - row * 20;
  const float* rr = rnn + (size_t)row * 512;
  const float* wr = linW + col * 512;
  float acc = linb[col];
  for (int k8 = 0; k8 < 64; k8++){
    float4 ra = *(const float4*)(rr + k8 * 8);
    float4 rb = *(const float4*)(rr + k8 * 8 + 4);
    float4 wa = *(const float4*)(wr + k8 * 8);
    float4 wb = *(const float4*)(wr + k8 * 8 + 4);
    acc += ra.x * wa.x + ra.y * wa.y + ra.z * wa.z + ra.w * wa.w
         + rb.x * wb.x + rb.y * wb.y + rb.z * wb.z + rb.w * wb.w;
  }
  feats[id] = acc;
}

// ---- K4: CRF numerator + forward scan. One WG (1 wave) per batch.
__global__ __launch_bounds__(64) void crf_kernel(const int* __restrict__ tags,
    const int* __restrict__ lengths, const float* __restrict__ trans,
    const float* __restrict__ feats, float* __restrict__ out){
  int b = blockIdx.x, tid = threadIdx.x;
  __shared__ float tr[400];
  __shared__ float sc[20];
  for (int i = tid; i < 400; i += 64) tr[i] = trans[i];
  __syncthreads();
  int l = lengths[b];
  const int* tg = tags + b * SS;
  const float* fb = feats + (size_t)b * SS * 20;
  // numerator
  float p = 0.f;
  for (int s = tid; s < SS; s += 64){
    if (s < l){
      int cur = tg[s];
      int prev = s ? tg[s - 1] : SOS_IDX;
      p += fb[s * 20 + cur] + tr[cur * 20 + prev];
    }
  }
  #pragma unroll
  for (int off = 32; off; off >>= 1) p += __shfl_down(p, off);
  if (tid < 20) sc[tid] = (tid == SOS_IDX) ? 0.f : NEGV;
  __syncthreads();
  for (int s = 0; s < l; s++){
    float nv = 0.f;
    if (tid < 20){
      float em = fb[s * 20 + tid];
      const float* trow = &tr[tid * 20];
      float v[20];
      float m = -1e30f;
      #pragma unroll
      for (int jj = 0; jj < 20; jj++){ v[jj] = sc[jj] + trow[jj]; m = fmaxf(m, v[jj]); }
      float ssum = 0.f;
      #pragma unroll
      for (int jj = 0; jj < 20; jj++) ssum += __expf(v[jj] - m);
      nv = em + m + __logf(ssum);
    }
    __syncthreads();
    if (tid < 20) sc[tid] = nv;
    __syncthreads();
  }
  if (tid == 0){
    float m = -1e30f;
    #pragma unroll
    for (int i = 0; i < 20; i++) m = fmaxf(m, sc[i]);
    float ssum = 0.f;
    #pragma unroll
    for (int i = 0; i < 20; i++) ssum += __expf(sc[i] - m);
    out[b] = (m + __logf(ssum)) - p;
  }
}

extern "C" void kernel_launch(void* const* d_in, const int* in_sizes, int n_in,
                              void* d_out, int out_size, void* d_ws, size_t ws_size,
                              hipStream_t stream){
  const int*   word_seq = (const int*)d_in[0];
  const int*   tags     = (const int*)d_in[1];
  const int*   lengths  = (const int*)d_in[2];
  const float* embed    = (const float*)d_in[3];
  const float* wih_f    = (const float*)d_in[4];
  const float* whh_f    = (const float*)d_in[5];
  const float* b_f      = (const float*)d_in[6];
  const float* wih_b    = (const float*)d_in[7];
  const float* whh_b    = (const float*)d_in[8];
  const float* b_b      = (const float*)d_in[9];
  const float* linW     = (const float*)d_in[10];
  const float* linb     = (const float*)d_in[11];
  const float* trans    = (const float*)d_in[12];
  float* out = (float*)d_out;

  // workspace layout (total ~197.5 MB)
  char* ws = (char*)d_ws;
  float*          wt2   = (float*)ws;                                            // 2 MB (W_hh f32 repack)
  float*          wt    = (float*)(ws + (2ull << 20));                           // 1 MB (W_ih transposed)
  unsigned short* xg    = (unsigned short*)(ws + (3ull << 20));                  // 128 MB (bf16)
  float*          rnn   = (float*)(ws + (3ull << 20) + 134217728ull);            // 64 MB (f32)
  float*          feats = (float*)(ws + (3ull << 20) + 134217728ull + 67108864ull); // 2.5 MB

  prep_whh<<<dim3(2048), dim3(256), 0, stream>>>(whh_f, whh_b, wt2);
  prep_wih<<<dim3(1024), dim3(256), 0, stream>>>(wih_f, wih_b, wt);
  xg_gemm<<<dim3(4096), dim3(256), 0, stream>>>(word_seq, embed, wt, b_f, b_b, xg);
  lstm_seq<<<dim3(128), dim3(1024), 0, stream>>>(lengths, wt2, xg, rnn);
  feat_gemv<<<dim3(2560), dim3(256), 0, stream>>>(rnn, linW, linb, feats);
  crf_kernel<<<dim3(64), dim3(64), 0, stream>>>(tags, lengths, trans, feats, out);
}

// Round 4
// 1776.320 us; speedup vs baseline: 5.8080x; 5.8080x over previous
//
#include <hip/hip_runtime.h>
#include <hip/hip_fp16.h>
#include <stdint.h>

// Problem constants
#define BB 64
#define SS 512
#define EE 128
#define HH 256
#define KK 20
#define NEGV -9999.0f
#define SOS_IDX 19

typedef unsigned int u32;

__device__ __forceinline__ float sigm(float x){ return 1.0f / (1.0f + __expf(-x)); }
__device__ __forceinline__ float tanh_fast(float x){
  float e = __expf(2.f * x);          // x->+inf: e=inf -> 1; x->-inf: e=0 -> -1
  return 1.f - 2.f / (e + 1.f);
}

// 4 packed fma: w (uint4 = 8 f16) * h (4 half2 from LDS, broadcast) -> 4 half2 accs
__device__ __forceinline__ void pk4(uint4 w, const __half2* hp,
                                    __half2& a0, __half2& a1, __half2& a2, __half2& a3){
  __half2 w0 = *(__half2*)&w.x, w1 = *(__half2*)&w.y, w2 = *(__half2*)&w.z, w3 = *(__half2*)&w.w;
  a0 = __hfma2(w0, hp[0], a0);
  a1 = __hfma2(w1, hp[1], a1);
  a2 = __hfma2(w2, hp[2], a2);
  a3 = __hfma2(w3, hp[3], a3);
}
__device__ __forceinline__ float flushacc(__half2& a0, __half2& a1, __half2& a2, __half2& a3){
  float2 f0 = __half22float2(a0), f1 = __half22float2(a1);
  float2 f2 = __half22float2(a2), f3 = __half22float2(a3);
  __half2 z = __floats2half2_rn(0.f, 0.f);
  a0 = z; a1 = z; a2 = z; a3 = z;
  return ((f0.x + f0.y) + (f1.x + f1.y)) + ((f2.x + f2.y) + (f3.x + f3.y));
}

// ---- K0a: pack W_hh (f32 [1024][256]) -> f16 wp[d][chunk(32)][row(1024)][8]
// chunk c covers k = 8c..8c+7. Chunks 0..5 -> VGPR, 6..14 -> LDS, 15..31 -> streamed.
__global__ void prep_whh(const float* __restrict__ whh_f, const float* __restrict__ whh_b,
                         __half* __restrict__ wp){
  int id = blockIdx.x * 256 + threadIdx.x;      // 2*1024*256 = 524288
  if (id >= 524288) return;
  int d = id >> 18;
  int rem = id & 262143;
  int row = rem >> 8;
  int k = rem & 255;
  const float* w = d ? whh_b : whh_f;
  wp[(((size_t)d * 32 + (k >> 3)) * 1024 + row) * 8 + (k & 7)] = __float2half(w[row * 256 + k]);
}

// ---- K0b: transpose W_ih -> wt[k(128)][2048] f32 (cols 0..1023 fwd, 1024..2047 bwd)
__global__ void prep_wih(const float* __restrict__ wih_f, const float* __restrict__ wih_b,
                         float* __restrict__ wt){
  int id = blockIdx.x * 256 + threadIdx.x;      // 2*1024*128 = 262144
  if (id >= 262144) return;
  int d = id >> 17;
  int rem = id & 131071;
  int col = rem >> 7;
  int k = rem & 127;
  const float* w = d ? wih_b : wih_f;
  wt[(size_t)k * 2048 + d * 1024 + col] = w[col * 128 + k];
}

// ---- K1: xg = embed[word] @ W_ih.T + b, both dirs, stored f16.
__global__ __launch_bounds__(256) void xg_gemm(const int* __restrict__ word_seq,
    const float* __restrict__ embed, const float* __restrict__ wt,
    const float* __restrict__ b_f, const float* __restrict__ b_b,
    __half* __restrict__ xg){
  __shared__ __align__(16) float xs[16][128];
  int rb = blockIdx.x >> 1, cb = blockIdx.x & 1;
  int tid = threadIdx.x;
  {
    int r = tid >> 4, kq = (tid & 15) * 8;
    int bs = rb * 16 + r;
    int w = word_seq[bs];
    const float* er = embed + (size_t)w * 128 + kq;
    float4 a = *(const float4*)er;
    float4 b = *(const float4*)(er + 4);
    *(float4*)&xs[r][kq] = a;
    *(float4*)&xs[r][kq + 4] = b;
  }
  __syncthreads();
  int co = tid * 4;
  const float* bias = cb ? b_b : b_f;
  float4 bv = *(const float4*)(bias + co);
  float4 acc[16];
  #pragma unroll
  for (int r = 0; r < 16; r++) acc[r] = bv;
  const float* wptr = wt + cb * 1024 + co;
  for (int k = 0; k < 128; k++){
    float4 w4 = *(const float4*)(wptr + (size_t)k * 2048);
    #pragma unroll
    for (int r = 0; r < 16; r++){
      float xv = xs[r][k];
      acc[r].x += xv * w4.x; acc[r].y += xv * w4.y;
      acc[r].z += xv * w4.z; acc[r].w += xv * w4.w;
    }
  }
  __half* base = xg + (size_t)cb * ((size_t)BB * SS * 1024);
  #pragma unroll
  for (int r = 0; r < 16; r++){
    int bs = rb * 16 + r;
    __half* o = base + (size_t)bs * 1024 + co;
    __half2 p0 = __floats2half2_rn(acc[r].x, acc[r].y);
    __half2 p1 = __floats2half2_rn(acc[r].z, acc[r].w);
    uint2 st; st.x = *(u32*)&p0; st.y = *(u32*)&p1;
    *(uint2*)o = st;
  }
}

// ---- K2: sequential LSTM, one WG (1024 thr = 16 waves) per (batch, dir).
// Thread tid owns gate-row tid. VGPR cap is 128 (4 waves/SIMD) -> weight tiers:
//   chunks 0..5   (k 0..47)    : VGPR (6 uint4 = 24 regs)
//   chunks 6..14  (k 48..119)  : LDS, thread-private rows, chunk-major (144 KB)
//   chunks 15..31 (k 120..255) : streamed from L2 each step, 4 rolling batches
//                                (peak 2x5 uint4 = 40 regs in flight)
__global__ __launch_bounds__(1024) void lstm_seq(const int* __restrict__ lengths,
    const __half* __restrict__ wp, const __half* __restrict__ xg,
    float* __restrict__ rnn){
  extern __shared__ __align__(16) char smem[];
  u32*     wl  = (u32*)smem;                    // 9*1024*16B = 147456
  float*   gl  = (float*)(smem + 147456);       // 4096
  __half2* hl2 = (__half2*)(smem + 151552);     // 512
  __half*  hlh = (__half*)(smem + 151552);

  int bx = blockIdx.x;
  int b = bx & 63, d = bx >> 6;
  int tid = threadIdx.x;
  int l = lengths[b];
  const uint4* wp4 = (const uint4*)(wp + (size_t)d * (32 * 1024 * 8));

  // VGPR-resident chunks 0..5
  uint4 wr[6];
  #pragma unroll
  for (int c = 0; c < 6; c++) wr[c] = wp4[c * 1024 + tid];
  // LDS chunks 6..14
  #pragma unroll
  for (int c = 0; c < 9; c++){
    uint4 v = wp4[(6 + c) * 1024 + tid];
    *(uint4*)&wl[(c * 1024 + tid) * 4] = v;
  }
  if (tid < 256) hlh[tid] = __float2half(0.f);
  float cc = 0.f;
  const __half* xgd = xg + ((size_t)d * BB * SS + (size_t)b * SS) * 1024;
  float* rbp = rnn + (size_t)b * SS * 512 + d * 256;
  for (int i = tid; i < (SS - l) * 256; i += 1024){
    int s = l + (i >> 8), j = i & 255;
    rbp[(size_t)s * 512 + j] = 0.f;
  }
  int gate = tid >> 8;                 // wave-uniform (256-aligned)
  const uint4* sp4 = wp4 + 15 * 1024;  // stream chunks 15..31
  __syncthreads();

  for (int t = 0; t < l; t++){
    int s = d ? (l - 1 - t) : t;
    float xv = __half2float(xgd[(size_t)s * 1024 + tid]);
    // prefetch batch 0 (chunks 15..19)
    uint4 s0[5];
    #pragma unroll
    for (int c = 0; c < 5; c++) s0[c] = sp4[c * 1024 + tid];

    __half2 z = __floats2half2_rn(0.f, 0.f);
    __half2 a0 = z, a1 = z, a2 = z, a3 = z;
    float fa;
    // phase V: VGPR chunks 0..5, h[0..47]
    #pragma unroll
    for (int c = 0; c < 6; c++) pk4(wr[c], hl2 + c * 4, a0, a1, a2, a3);
    fa = flushacc(a0, a1, a2, a3);
    // prefetch batch 1 (chunks 20..24)
    uint4 s1[5];
    #pragma unroll
    for (int c = 0; c < 5; c++) s1[c] = sp4[(5 + c) * 1024 + tid];
    // phase L: LDS chunks 6..14, h[48..119]
    #pragma unroll
    for (int c = 0; c < 9; c++){
      uint4 wv = *(const uint4*)&wl[(c * 1024 + tid) * 4];
      pk4(wv, hl2 + 24 + c * 4, a0, a1, a2, a3);
    }
    fa += flushacc(a0, a1, a2, a3);
    // phase S0: consume batch 0 (chunks 15..19), h[120..159]
    #pragma unroll
    for (int c = 0; c < 5; c++) pk4(s0[c], hl2 + 60 + c * 4, a0, a1, a2, a3);
    // prefetch batch 2 into s0 (chunks 25..29)
    #pragma unroll
    for (int c = 0; c < 5; c++) s0[c] = sp4[(10 + c) * 1024 + tid];
    // phase S1: consume batch 1 (chunks 20..24), h[160..199]
    #pragma unroll
    for (int c = 0; c < 5; c++) pk4(s1[c], hl2 + 80 + c * 4, a0, a1, a2, a3);
    // prefetch batch 3 into s1[0..1] (chunks 30..31)
    s1[0] = sp4[15 * 1024 + tid];
    s1[1] = sp4[16 * 1024 + tid];
    fa += flushacc(a0, a1, a2, a3);
    // phase S2: consume batch 2 (chunks 25..29), h[200..239]
    #pragma unroll
    for (int c = 0; c < 5; c++) pk4(s0[c], hl2 + 100 + c * 4, a0, a1, a2, a3);
    // phase S3: consume batch 3 (chunks 30..31), h[240..255]
    pk4(s1[0], hl2 + 120, a0, a1, a2, a3);
    pk4(s1[1], hl2 + 124, a0, a1, a2, a3);
    fa += flushacc(a0, a1, a2, a3);

    float a = fa + xv;
    float gv = (gate == 2) ? tanh_fast(a) : sigm(a);
    gl[tid] = gv;
    __syncthreads();
    if (tid < 256){
      float iv = gl[tid], fv = gl[tid + 256], gg = gl[tid + 512], ov = gl[tid + 768];
      cc = fv * cc + iv * gg;
      float h = ov * tanh_fast(cc);
      hlh[tid] = __float2half(h);
      rbp[(size_t)s * 512 + tid] = h;
    }
    __syncthreads();
  }
}

// ---- K3: feats = rnn_out @ lin_W.T + lin_b  (one thread per (row,col)), rnn f32
__global__ void feat_gemv(const float* __restrict__ rnn,
    const float* __restrict__ linW, const float* __restrict__ linb,
    float* __restrict__ feats){
  int id = blockIdx.x * 256 + threadIdx.x;
  if (id >= BB * SS * KK) return;
  int row = id / 20;
  int col = id - row * 20;
  const float* rr = rnn + (size_t)row * 512;
  const float* wr = linW + col * 512;
  float acc = linb[col];
  for (int k8 = 0; k8 < 64; k8++){
    float4 ra = *(const float4*)(rr + k8 * 8);
    float4 rb = *(const float4*)(rr + k8 * 8 + 4);
    float4 wa = *(const float4*)(wr + k8 * 8);
    float4 wb = *(const float4*)(wr + k8 * 8 + 4);
    acc += ra.x * wa.x + ra.y * wa.y + ra.z * wa.z + ra.w * wa.w
         + rb.x * wb.x + rb.y * wb.y + rb.z * wb.z + rb.w * wb.w;
  }
  feats[id] = acc;
}

// ---- K4: CRF numerator + forward scan. One WG (1 wave) per batch.
__global__ __launch_bounds__(64) void crf_kernel(const int* __restrict__ tags,
    const int* __restrict__ lengths, const float* __restrict__ trans,
    const float* __restrict__ feats, float* __restrict__ out){
  int b = blockIdx.x, tid = threadIdx.x;
  __shared__ float tr[400];
  __shared__ float sc[20];
  for (int i = tid; i < 400; i += 64) tr[i] = trans[i];
  __syncthreads();
  int l = lengths[b];
  const int* tg = tags + b * SS;
  const float* fb = feats + (size_t)b * SS * 20;
  // numerator
  float p = 0.f;
  for (int s = tid; s < SS; s += 64){
    if (s < l){
      int cur = tg[s];
      int prev = s ? tg[s - 1] : SOS_IDX;
      p += fb[s * 20 + cur] + tr[cur * 20 + prev];
    }
  }
  #pragma unroll
  for (int off = 32; off; off >>= 1) p += __shfl_down(p, off);
  if (tid < 20) sc[tid] = (tid == SOS_IDX) ? 0.f : NEGV;
  __syncthreads();
  float em = (tid < 20 && l > 0) ? fb[tid] : 0.f;   // prefetched emission for s=0
  for (int s = 0; s < l; s++){
    float em_nxt = (tid < 20 && (s + 1) < l) ? fb[(s + 1) * 20 + tid] : 0.f;
    float nv = 0.f;
    if (tid < 20){
      const float* trow = &tr[tid * 20];
      float v[20];
      float m = -1e30f;
      #pragma unroll
      for (int jj = 0; jj < 20; jj++){ v[jj] = sc[jj] + trow[jj]; m = fmaxf(m, v[jj]); }
      float ssum = 0.f;
      #pragma unroll
      for (int jj = 0; jj < 20; jj++) ssum += __expf(v[jj] - m);
      nv = em + m + __logf(ssum);
    }
    __syncthreads();
    if (tid < 20) sc[tid] = nv;
    __syncthreads();
    em = em_nxt;
  }
  if (tid == 0){
    float m = -1e30f;
    #pragma unroll
    for (int i = 0; i < 20; i++) m = fmaxf(m, sc[i]);
    float ssum = 0.f;
    #pragma unroll
    for (int i = 0; i < 20; i++) ssum += __expf(sc[i] - m);
    out[b] = (m + __logf(ssum)) - p;
  }
}

extern "C" void kernel_launch(void* const* d_in, const int* in_sizes, int n_in,
                              void* d_out, int out_size, void* d_ws, size_t ws_size,
                              hipStream_t stream){
  const int*   word_seq = (const int*)d_in[0];
  const int*   tags     = (const int*)d_in[1];
  const int*   lengths  = (const int*)d_in[2];
  const float* embed    = (const float*)d_in[3];
  const float* wih_f    = (const float*)d_in[4];
  const float* whh_f    = (const float*)d_in[5];
  const float* b_f      = (const float*)d_in[6];
  const float* wih_b    = (const float*)d_in[7];
  const float* whh_b    = (const float*)d_in[8];
  const float* b_b      = (const float*)d_in[9];
  const float* linW     = (const float*)d_in[10];
  const float* linb     = (const float*)d_in[11];
  const float* trans    = (const float*)d_in[12];
  float* out = (float*)d_out;

  // workspace layout (~196.5 MiB)
  // xg is 2*64*512*1024 f16 = 134,217,728 B = 128 MiB (round-3 bug: was placed
  // as if 64 MiB -> rnn overlapped xg's d=1 half -> NaN).
  char* ws = (char*)d_ws;
  __half* wp    = (__half*)ws;                                         // 1 MiB
  float*  wt    = (float*)(ws + (1ull << 20));                         // 1 MiB
  __half* xg    = (__half*)(ws + (2ull << 20));                        // 128 MiB
  float*  rnn   = (float*)(ws + (2ull << 20) + (128ull << 20));        // 64 MiB
  float*  feats = (float*)(ws + (2ull << 20) + (192ull << 20));        // 2.5 MiB

  (void)hipFuncSetAttribute((const void*)lstm_seq,
        hipFuncAttributeMaxDynamicSharedMemorySize, 152064);

  prep_whh<<<dim3(2048), dim3(256), 0, stream>>>(whh_f, whh_b, wp);
  prep_wih<<<dim3(1024), dim3(256), 0, stream>>>(wih_f, wih_b, wt);
  xg_gemm<<<dim3(4096), dim3(256), 0, stream>>>(word_seq, embed, wt, b_f, b_b, xg);
  lstm_seq<<<dim3(128), dim3(1024), 152064, stream>>>(lengths, wp, xg, rnn);
  feat_gemv<<<dim3(2560), dim3(256), 0, stream>>>(rnn, linW, linb, feats);
  crf_kernel<<<dim3(64), dim3(64), 0, stream>>>(tags, lengths, trans, feats, out);
}